// Round 11
// baseline (1079.955 us; speedup 1.0000x reference)
//
#include <hip/hip_runtime.h>
#include <hip/hip_cooperative_groups.h>

#define HH 512
#define WW 512
#define NIMG 12
#define RAD 3
#define TW 64
#define TH 16
#define LW (TW + 2*RAD)   // 70
#define LH (TH + 2*RAD)   // 22
#define RPW 4             // consecutive output rows per wave (TH / 4 waves)
#define NBLK 768          // persistent blocks: 3/CU (HW capacity is 8/CU at
                          // VGPR=64, LDS 12.8KB -> huge co-residency margin)
#define TPB 4             // tiles per block per iteration; 768*4 = 3072 tiles

namespace cg = cooperative_groups;

// Side-window filter, 6 iterations.
//
// NUMERICS CONTRACT (established R1-R5, frozen):
//  - Grading ref is an fp32 replay; conv = sequential fma over the 7x7
//    window in (ky,kx) row-major order, one accumulator (R4: bit-exact).
//  - IM chains determine argmin + dm -> keep that exact order (176 fma/px).
//  - PERT is selection-independent -> quadrant decomposition with row
//    partials hl=(b0+b1)+(b2+b3), hr=(b3+b4)+(b5+b6) (absmax 9.77e-4).
//
// PERF MODEL (R4-R9 fit): dispatch = work(~17us) + FIXED(~23us boundary).
// R10's cooperative single-launch failed SILENTLY (no error check; output
// never written). This round: typed launch + return-code check + fallback
// to the proven 6-dispatch path inside the same kernel_launch call.
// Both paths share swf_tile() -> identical numerics.

__device__ __forceinline__ void swf_tile(
    const float* __restrict__ iin, const float* __restrict__ pin,
    float* __restrict__ iout, float* __restrict__ pout,
    int bx, int by, int bz, int tid,
    float (*sI)[LW], float (*sP)[LW])
{
    const int x0 = bx * TW;
    const int y0 = by * TH;
    const size_t base = (size_t)bz * (size_t)(HH * WW);
    const float* imb = iin + base;
    const float* peb = pin + base;

    __syncthreads();   // all waves done with LDS from the previous tile
    for (int i = tid; i < LH * LW; i += 256) {
        int r = i / LW;
        int c = i - r * LW;
        int gy = y0 - RAD + r;
        int gx = x0 - RAD + c;
        bool ok = ((unsigned)gy < (unsigned)HH) && ((unsigned)gx < (unsigned)WW);
        int gi = gy * WW + gx;
        sI[r][c] = ok ? imb[gi] : 0.0f;
        sP[r][c] = ok ? peb[gi] : 0.0f;
    }
    __syncthreads();

    const float w28 = 1.0f / 28.0f;   // fp32-rounded, as in the ref's kernels
    const float w16 = 0.0625f;        // exact
    const int tx = tid & 63;
    const int wv = tid >> 6;          // wave id 0..3
    const int r0 = wv * RPW;          // wave's slab: sI rows r0 .. r0+RPW+5

    // Phase-rotated register rings; slot for raw row m is m%7.
    float wi[7][7];                   // im taps
    float hl[7], hr[7], cc[7];        // pert row partials + center column

    #pragma unroll
    for (int m = 0; m < 7; ++m) {
        #pragma unroll
        for (int dx = 0; dx < 7; ++dx)
            wi[m][dx] = sI[r0 + m][tx + dx];
        float b0 = sP[r0 + m][tx],     b1 = sP[r0 + m][tx + 1],
              b2 = sP[r0 + m][tx + 2], b3 = sP[r0 + m][tx + 3],
              b4 = sP[r0 + m][tx + 4], b5 = sP[r0 + m][tx + 5],
              b6 = sP[r0 + m][tx + 6];
        hl[m] = (b0 + b1) + (b2 + b3);
        hr[m] = (b3 + b4) + (b5 + b6);
        cc[m] = b3;
    }

    #pragma unroll
    for (int jj = 0; jj < RPW; ++jj) {
        // im: 8 exact sequential fma chains, rows dy=0..6 in slot (jj+dy)%7,
        // row-major tap order within each chain
        float d[8];
        {
            float sL = 0.f, sR = 0.f, sU = 0.f, sD = 0.f;
            float sNW = 0.f, sNE = 0.f, sSW = 0.f, sSE = 0.f;
            #pragma unroll
            for (int dy = 0; dy < 7; ++dy) {
                const int s = (jj + dy) % 7;
                #pragma unroll
                for (int dx = 0; dx < 4; ++dx)
                    sL = fmaf(wi[s][dx], w28, sL);
                #pragma unroll
                for (int dx = 3; dx < 7; ++dx)
                    sR = fmaf(wi[s][dx], w28, sR);
            }
            #pragma unroll
            for (int dy = 0; dy < 4; ++dy) {
                const int s = (jj + dy) % 7;
                #pragma unroll
                for (int dx = 0; dx < 7; ++dx)
                    sU = fmaf(wi[s][dx], w28, sU);
                #pragma unroll
                for (int dx = 0; dx < 4; ++dx)
                    sNW = fmaf(wi[s][dx], w16, sNW);
                #pragma unroll
                for (int dx = 3; dx < 7; ++dx)
                    sNE = fmaf(wi[s][dx], w16, sNE);
            }
            #pragma unroll
            for (int dy = 3; dy < 7; ++dy) {
                const int s = (jj + dy) % 7;
                #pragma unroll
                for (int dx = 0; dx < 7; ++dx)
                    sD = fmaf(wi[s][dx], w28, sD);
                #pragma unroll
                for (int dx = 0; dx < 4; ++dx)
                    sSW = fmaf(wi[s][dx], w16, sSW);
                #pragma unroll
                for (int dx = 3; dx < 7; ++dx)
                    sSE = fmaf(wi[s][dx], w16, sSE);
            }
            const float cI = wi[(jj + 3) % 7][3];
            d[0] = sL - cI;  d[1] = sR - cI;  d[2] = sU - cI;  d[3] = sD - cI;
            d[4] = sNW - cI; d[5] = sNE - cI; d[6] = sSW - cI; d[7] = sSE - cI;
        }

        // pert: quadrant decomposition (bit-identical to R5/R8)
        float e[8];
        const int p0 = (jj + 0) % 7, p1 = (jj + 1) % 7, p2 = (jj + 2) % 7,
                  p3 = (jj + 3) % 7, p4 = (jj + 4) % 7, p5 = (jj + 5) % 7,
                  p6 = (jj + 6) % 7;
        {
            float qnw = ((hl[p0] + hl[p1]) + (hl[p2] + hl[p3]));
            float qsw = ((hl[p3] + hl[p4]) + (hl[p5] + hl[p6]));
            float qne = ((hr[p0] + hr[p1]) + (hr[p2] + hr[p3]));
            float qse = ((hr[p3] + hr[p4]) + (hr[p5] + hr[p6]));
            float cu  = ((cc[p0] + cc[p1]) + (cc[p2] + cc[p3]));
            float cd  = ((cc[p3] + cc[p4]) + (cc[p5] + cc[p6]));
            float cP  = cc[p3];
            e[0] = (qnw + qsw - hl[p3]) * w28 - cP;
            e[1] = (qne + qse - hr[p3]) * w28 - cP;
            e[2] = (qnw + qne - cu)     * w28 - cP;
            e[3] = (qsw + qse - cd)     * w28 - cP;
            e[4] = qnw * w16 - cP;
            e[5] = qne * w16 - cP;
            e[6] = qsw * w16 - cP;
            e[7] = qse * w16 - cP;
        }

        // first-index-wins argmin over |d| (jnp.argmin tie-break)
        float bestAbs = fabsf(d[0]);
        float bd = d[0];
        float be = e[0];
        #pragma unroll
        for (int j = 1; j < 8; ++j) {
            float a = fabsf(d[j]);
            bool take = a < bestAbs;
            bestAbs = take ? a : bestAbs;
            bd = take ? d[j] : bd;
            be = take ? e[j] : be;
        }

        const int gy = y0 + r0 + jj;
        const int gx = x0 + tx;
        const size_t gi = base + (size_t)gy * WW + gx;
        iout[gi] = wi[(jj + 3) % 7][3] + bd;   // bit-exact im chain
        pout[gi] = cc[p3] + be;                // pert drift ~1e-6/iter

        // slide: raw row r0+jj+7 into slot jj%7
        if (jj < RPW - 1) {
            const int m = r0 + jj + 7;
            const int slot = jj % 7;
            #pragma unroll
            for (int dx = 0; dx < 7; ++dx)
                wi[slot][dx] = sI[m][tx + dx];
            float b0 = sP[m][tx],     b1 = sP[m][tx + 1], b2 = sP[m][tx + 2],
                  b3 = sP[m][tx + 3], b4 = sP[m][tx + 4], b5 = sP[m][tx + 5],
                  b6 = sP[m][tx + 6];
            hl[slot] = (b0 + b1) + (b2 + b3);
            hr[slot] = (b3 + b4) + (b5 + b6);
            cc[slot] = b3;
        }
    }
}

// Fallback: one iteration per dispatch (proven R8 path, 40.3us/dispatch)
__global__ __launch_bounds__(256) void swf_step(
    const float* __restrict__ im_in, const float* __restrict__ pe_in,
    float* __restrict__ im_out, float* __restrict__ pe_out)
{
    __shared__ float sI[LH][LW];
    __shared__ float sP[LH][LW];
    swf_tile(im_in, pe_in, im_out, pe_out,
             blockIdx.x, blockIdx.y, blockIdx.z, threadIdx.x, sI, sP);
}

// Preferred: all 6 iterations, one cooperative launch, grid.sync between.
__global__ __launch_bounds__(256, 4) void swf_all(
    const float* __restrict__ im0, const float* __restrict__ pe0,
    float* __restrict__ imA, float* __restrict__ imB,
    float* __restrict__ peA, float* __restrict__ out)
{
    cg::grid_group grid = cg::this_grid();
    __shared__ float sI[LH][LW];
    __shared__ float sP[LH][LW];

    for (int it = 0; it < 6; ++it) {
        const float* iin;  const float* pin;  float* iout;  float* pout;
        if (it == 0)     { iin = im0; pin = pe0; iout = imA; pout = peA; }
        else if (it & 1) { iin = imA; pin = peA; iout = imB; pout = out; }
        else             { iin = imB; pin = out; iout = imA; pout = peA; }

        for (int tt = 0; tt < TPB; ++tt) {
            const int tile = blockIdx.x * TPB + tt;   // 0..3071, consecutive
            swf_tile(iin, pin, iout, pout,
                     tile & 7, (tile >> 3) & 31, tile >> 8, threadIdx.x,
                     sI, sP);
        }
        if (it < 5) {
            __threadfence();   // device-scope release of this iter's stores
            grid.sync();       // grid-wide barrier (cooperative launch)
        }
    }
}

extern "C" void kernel_launch(void* const* d_in, const int* in_sizes, int n_in,
                              void* d_out, int out_size, void* d_ws, size_t ws_size,
                              hipStream_t stream) {
    const float* im0 = (const float*)d_in[0];
    const float* pe0 = (const float*)d_in[1];
    float* out = (float*)d_out;

    const size_t npix = (size_t)NIMG * HH * WW;   // 3,145,728
    float* imA = (float*)d_ws;                    // 12.6 MB
    float* imB = imA + npix;                      // 12.6 MB
    float* peA = (float*)(imB + npix);            // 12.6 MB (ws total 37.7 MB)
    // d_out doubles as the odd-iteration pert buffer; it5 lands final pert.

    void* args[] = {(void*)&im0, (void*)&pe0, (void*)&imA,
                    (void*)&imB, (void*)&peA, (void*)&out};
    hipError_t rc = hipLaunchCooperativeKernel(
        swf_all, dim3(NBLK), dim3(256), args, 0, stream);

    if (rc != hipSuccess) {
        // Fallback: proven 6-dispatch ping-pong (identical numerics).
        float* peB = out;
        dim3 grid(WW / TW, HH / TH, NIMG);        // 8 x 32 x 12 = 3072 blocks
        dim3 block(256);
        swf_step<<<grid, block, 0, stream>>>(im0, pe0, imA, peA);  // it0
        swf_step<<<grid, block, 0, stream>>>(imA, peA, imB, peB);  // it1
        swf_step<<<grid, block, 0, stream>>>(imB, peB, imA, peA);  // it2
        swf_step<<<grid, block, 0, stream>>>(imA, peA, imB, peB);  // it3
        swf_step<<<grid, block, 0, stream>>>(imB, peB, imA, peA);  // it4
        swf_step<<<grid, block, 0, stream>>>(imA, peA, imB, out);  // it5
    }
}

// Round 13
// 314.219 us; speedup vs baseline: 3.4369x; 3.4369x over previous
//
#include <hip/hip_runtime.h>

#define HH 512
#define WW 512
#define NIMG 12
#define RAD 3
#define TW 64
#define TH 16
#define RPW 4               // rows per wave in iter-b (TH / 4 waves)
// fused-tile geometry: core TH x TW; iter-b needs iter-a on +3 ring (mid),
// iter-a needs input on +6 ring (in).
#define SIH (TH + 4*RAD)    // 28  input-stage rows
#define SIW (TW + 4*RAD)    // 76  input-stage cols
#define SMH (TH + 2*RAD)    // 22  intermediate rows
#define SMW (TW + 2*RAD)    // 70  intermediate cols

// Side-window filter: 6 iterations as 3 dispatches (2 fused per dispatch).
//
// NUMERICS CONTRACT (R1-R5, frozen):
//  - Grading ref is an fp32 replay; conv = sequential fma over the 7x7
//    window in (ky,kx) row-major order, one accumulator (R4: bit-exact).
//  - IM chains determine argmin + dm -> keep that exact order (176 fma/px).
//    Per-pixel pure function of the raw window -> tiling-independent, so
//    halo-recomputed values match exactly.
//  - PERT is selection-independent -> quadrant decomposition with row
//    partials hl=(b0+b1)+(b2+b3), hr=(b3+b4)+(b5+b6) (absmax 9.77e-4).
//
// PERF HISTORY: 6-dispatch floor 235us (R9); fit dispatch = work 17us +
// fixed 22us. Coop single-launch: R10 silent fail, R11 1043us (occupancy+
// cg::sync cost), R12 harness crash (coop launch is incompatible with
// graph capture). This round: halo-recompute fusion, 3 plain dispatches.
// Iter-a recompute ratio 22x70/16x64 = 1.50 (iter-a only).
// LDS 29.3KB/block -> 5 blocks/CU; grid 3072 x 256 (proven R5 shape).

__device__ __forceinline__ void swf_px(
    const float w[7][7],          // raw 7x7 im window, row-major
    float hl[7], float hr[7],     // pert row partials (cols 0..3 / 3..6)
    float cc[7],                  // pert center column (col 3)
    float& outI, float& outP)
{
    const float w28 = 1.0f / 28.0f;   // fp32-rounded, as in the ref kernels
    const float w16 = 0.0625f;        // exact

    // im: 8 exact sequential fma chains, (ky,kx) row-major per chain
    float d[8];
    {
        float sL = 0.f, sR = 0.f, sU = 0.f, sD = 0.f;
        float sNW = 0.f, sNE = 0.f, sSW = 0.f, sSE = 0.f;
        #pragma unroll
        for (int dy = 0; dy < 7; ++dy) {
            #pragma unroll
            for (int dx = 0; dx < 4; ++dx)
                sL = fmaf(w[dy][dx], w28, sL);
            #pragma unroll
            for (int dx = 3; dx < 7; ++dx)
                sR = fmaf(w[dy][dx], w28, sR);
        }
        #pragma unroll
        for (int dy = 0; dy < 4; ++dy) {
            #pragma unroll
            for (int dx = 0; dx < 7; ++dx)
                sU = fmaf(w[dy][dx], w28, sU);
            #pragma unroll
            for (int dx = 0; dx < 4; ++dx)
                sNW = fmaf(w[dy][dx], w16, sNW);
            #pragma unroll
            for (int dx = 3; dx < 7; ++dx)
                sNE = fmaf(w[dy][dx], w16, sNE);
        }
        #pragma unroll
        for (int dy = 3; dy < 7; ++dy) {
            #pragma unroll
            for (int dx = 0; dx < 7; ++dx)
                sD = fmaf(w[dy][dx], w28, sD);
            #pragma unroll
            for (int dx = 0; dx < 4; ++dx)
                sSW = fmaf(w[dy][dx], w16, sSW);
            #pragma unroll
            for (int dx = 3; dx < 7; ++dx)
                sSE = fmaf(w[dy][dx], w16, sSE);
        }
        const float cI = w[3][3];
        d[0] = sL - cI;  d[1] = sR - cI;  d[2] = sU - cI;  d[3] = sD - cI;
        d[4] = sNW - cI; d[5] = sNE - cI; d[6] = sSW - cI; d[7] = sSE - cI;
        outI = cI;   // caller adds bd
    }

    // pert: quadrant decomposition (bit-identical formulas to R5/R8)
    float e[8];
    {
        float qnw = ((hl[0] + hl[1]) + (hl[2] + hl[3]));
        float qsw = ((hl[3] + hl[4]) + (hl[5] + hl[6]));
        float qne = ((hr[0] + hr[1]) + (hr[2] + hr[3]));
        float qse = ((hr[3] + hr[4]) + (hr[5] + hr[6]));
        float cu  = ((cc[0] + cc[1]) + (cc[2] + cc[3]));
        float cd  = ((cc[3] + cc[4]) + (cc[5] + cc[6]));
        float cP  = cc[3];
        e[0] = (qnw + qsw - hl[3]) * w28 - cP;
        e[1] = (qne + qse - hr[3]) * w28 - cP;
        e[2] = (qnw + qne - cu)    * w28 - cP;
        e[3] = (qsw + qse - cd)    * w28 - cP;
        e[4] = qnw * w16 - cP;
        e[5] = qne * w16 - cP;
        e[6] = qsw * w16 - cP;
        e[7] = qse * w16 - cP;
        outP = cP;   // caller adds be
    }

    // first-index-wins argmin over |d| (jnp.argmin tie-break)
    float bestAbs = fabsf(d[0]);
    float bd = d[0];
    float be = e[0];
    #pragma unroll
    for (int j = 1; j < 8; ++j) {
        float a = fabsf(d[j]);
        bool take = a < bestAbs;
        bestAbs = take ? a : bestAbs;
        bd = take ? d[j] : bd;
        be = take ? e[j] : be;
    }
    outI += bd;
    outP += be;
}

// Two fused side-window iterations per dispatch.
template <bool STORE_IM>
__global__ __launch_bounds__(256) void swf_fused(
    const float* __restrict__ im_in, const float* __restrict__ pe_in,
    float* __restrict__ im_out, float* __restrict__ pe_out)
{
    __shared__ float sIn[2][SIH][SIW];   // [0]=im, [1]=pert input stage
    __shared__ float sMd[2][SMH][SMW];   // iter-a result (intermediate)

    const int tid = threadIdx.x;
    const int x0 = blockIdx.x * TW;
    const int y0 = blockIdx.y * TH;
    const size_t base = (size_t)blockIdx.z * (size_t)(HH * WW);
    const float* imb = im_in + base;
    const float* peb = pe_in + base;

    // ---- stage input tile + 6-halo, zero-padded ----
    for (int i = tid; i < SIH * SIW; i += 256) {
        int r = i / SIW;
        int c = i - r * SIW;
        int gy = y0 - 2 * RAD + r;
        int gx = x0 - 2 * RAD + c;
        bool ok = ((unsigned)gy < (unsigned)HH) && ((unsigned)gx < (unsigned)WW);
        int gi = gy * WW + gx;
        sIn[0][r][c] = ok ? imb[gi] : 0.0f;
        sIn[1][r][c] = ok ? peb[gi] : 0.0f;
    }
    __syncthreads();

    // ---- iter-a: compute intermediate on SMH x SMW (flat over threads).
    //      Out-of-image intermediate px are ZERO (they act as the
    //      reference's zero padding for iter-b). ----
    for (int i = tid; i < SMH * SMW; i += 256) {
        int r = i / SMW;             // mid row; image row y0-3+r
        int c = i - r * SMW;         // mid col; image col x0-3+c
        int iy = y0 - RAD + r;
        int ix = x0 - RAD + c;
        bool inside = ((unsigned)iy < (unsigned)HH) && ((unsigned)ix < (unsigned)WW);
        float oI = 0.0f, oP = 0.0f;
        if (inside) {
            float w[7][7];
            float hl[7], hr[7], cc[7];
            #pragma unroll
            for (int dy = 0; dy < 7; ++dy) {
                #pragma unroll
                for (int dx = 0; dx < 7; ++dx)
                    w[dy][dx] = sIn[0][r + dy][c + dx];
                float b0 = sIn[1][r + dy][c],     b1 = sIn[1][r + dy][c + 1],
                      b2 = sIn[1][r + dy][c + 2], b3 = sIn[1][r + dy][c + 3],
                      b4 = sIn[1][r + dy][c + 4], b5 = sIn[1][r + dy][c + 5],
                      b6 = sIn[1][r + dy][c + 6];
                hl[dy] = (b0 + b1) + (b2 + b3);
                hr[dy] = (b3 + b4) + (b5 + b6);
                cc[dy] = b3;
            }
            swf_px(w, hl, hr, cc, oI, oP);
        }
        sMd[0][r][c] = oI;
        sMd[1][r][c] = oP;
    }
    __syncthreads();

    // ---- iter-b: core TH x TW via per-wave register ring over sMd ----
    const int tx = tid & 63;
    const int wv = tid >> 6;
    const int r0 = wv * RPW;         // wave rows r0..r0+RPW-1 of the core

    float wi[7][7];                  // im taps from sMd
    float hl[7], hr[7], cc[7];       // pert partials from sMd
    #pragma unroll
    for (int m = 0; m < 7; ++m) {
        #pragma unroll
        for (int dx = 0; dx < 7; ++dx)
            wi[m][dx] = sMd[0][r0 + m][tx + dx];
        float b0 = sMd[1][r0 + m][tx],     b1 = sMd[1][r0 + m][tx + 1],
              b2 = sMd[1][r0 + m][tx + 2], b3 = sMd[1][r0 + m][tx + 3],
              b4 = sMd[1][r0 + m][tx + 4], b5 = sMd[1][r0 + m][tx + 5],
              b6 = sMd[1][r0 + m][tx + 6];
        hl[m] = (b0 + b1) + (b2 + b3);
        hr[m] = (b3 + b4) + (b5 + b6);
        cc[m] = b3;
    }

    #pragma unroll
    for (int jj = 0; jj < RPW; ++jj) {
        // rotate ring into dy-order views (slot of raw row m is m%7)
        float w[7][7];
        float hl2[7], hr2[7], cc2[7];
        #pragma unroll
        for (int dy = 0; dy < 7; ++dy) {
            const int s = (jj + dy) % 7;
            #pragma unroll
            for (int dx = 0; dx < 7; ++dx)
                w[dy][dx] = wi[s][dx];
            hl2[dy] = hl[s];
            hr2[dy] = hr[s];
            cc2[dy] = cc[s];
        }
        float oI, oP;
        swf_px(w, hl2, hr2, cc2, oI, oP);

        const int gy = y0 + r0 + jj;
        const int gx = x0 + tx;
        const size_t gi = base + (size_t)gy * WW + gx;
        if (STORE_IM) im_out[gi] = oI;
        pe_out[gi] = oP;

        if (jj < RPW - 1) {
            const int m = r0 + jj + 7;      // <= 21 < SMH
            const int slot = jj % 7;
            #pragma unroll
            for (int dx = 0; dx < 7; ++dx)
                wi[slot][dx] = sMd[0][m][tx + dx];
            float b0 = sMd[1][m][tx],     b1 = sMd[1][m][tx + 1],
                  b2 = sMd[1][m][tx + 2], b3 = sMd[1][m][tx + 3],
                  b4 = sMd[1][m][tx + 4], b5 = sMd[1][m][tx + 5],
                  b6 = sMd[1][m][tx + 6];
            hl[slot] = (b0 + b1) + (b2 + b3);
            hr[slot] = (b3 + b4) + (b5 + b6);
            cc[slot] = b3;
        }
    }
}

extern "C" void kernel_launch(void* const* d_in, const int* in_sizes, int n_in,
                              void* d_out, int out_size, void* d_ws, size_t ws_size,
                              hipStream_t stream) {
    const float* im0 = (const float*)d_in[0];
    const float* pe0 = (const float*)d_in[1];
    float* out = (float*)d_out;

    const size_t npix = (size_t)NIMG * HH * WW;   // 3,145,728
    float* imA = (float*)d_ws;                    // 12.6 MB
    float* imB = imA + npix;                      // 12.6 MB
    float* peA = imB + npix;                      // 12.6 MB
    float* peB = peA + npix;                      // 12.6 MB (ws total 50.3 MB)

    dim3 grid(WW / TW, HH / TH, NIMG);            // 8 x 32 x 12 = 3072 blocks
    dim3 block(256);

    // 3 dispatches x 2 fused iterations; final pert lands in d_out, final
    // im store elided (result is pert only).
    swf_fused<true ><<<grid, block, 0, stream>>>(im0, pe0, imA, peA); // it0+1
    swf_fused<true ><<<grid, block, 0, stream>>>(imA, peA, imB, peB); // it2+3
    swf_fused<false><<<grid, block, 0, stream>>>(imB, peB, imA, out); // it4+5
}

// Round 14
// 312.442 us; speedup vs baseline: 3.4565x; 1.0057x over previous
//
#include <hip/hip_runtime.h>

#define HH 512
#define WW 512
#define NIMG 12
#define RAD 3
#define TW 64
#define TH 16
#define RPW 4               // rows per wave in iter-b (TH / 4 waves)
// fused-tile geometry: core TH x TW; iter-b needs iter-a values on a +3
// ring (22x70), iter-a needs raw input on a +6 ring (28x76).
#define SIH (TH + 4*RAD)    // 28  input-stage rows
#define SIW (TW + 4*RAD)    // 76  input-stage cols (logical)
#define SIP (SIW + 1)       // 77  padded LDS stride
#define SMH (TH + 2*RAD)    // 22  intermediate rows
#define SMW (TW + 2*RAD)    // 70  intermediate cols (logical)
#define SMP (SMW + 1)       // 71  padded LDS stride

// Side-window filter: 6 iterations as 3 dispatches (2 fused per dispatch).
//
// NUMERICS CONTRACT (R1-R5, frozen):
//  - Grading ref is an fp32 replay; conv = sequential fma over the 7x7
//    window in (ky,kx) row-major order, one accumulator (R4: bit-exact).
//  - IM chains determine argmin + dm -> keep that exact order (176 fma/px).
//    Per-pixel pure function of its raw window -> halo recompute is exact.
//  - PERT is selection-independent -> quadrant decomposition with row
//    partials hl=(b0+b1)+(b2+b3), hr=(b3+b4)+(b5+b6) (absmax 9.77e-4).
//
// PERF HISTORY: R9 6-dispatch = 235us (dispatch = ~20us VALU + ~20us
// ramp/stall). R13 fusion = 314us, leaks: ds_read_b128 4-way bank
// conflicts (5.85M cyc/dispatch) from array-passing + rotate-copy movs.
// This round: identical fusion skeleton, both phases inline with the
// R4/R8 load shapes that measured ZERO conflicts; LDS strides padded +1.
template <bool STORE_IM>
__global__ __launch_bounds__(256) void swf_fused(
    const float* __restrict__ im_in, const float* __restrict__ pe_in,
    float* __restrict__ im_out, float* __restrict__ pe_out)
{
    __shared__ float sI0[SIH][SIP];   // raw im
    __shared__ float sP0[SIH][SIP];   // raw pert
    __shared__ float sIm[SMH][SMP];   // iter-a im result
    __shared__ float sPm[SMH][SMP];   // iter-a pert result

    const int tid = threadIdx.x;
    const int x0 = blockIdx.x * TW;
    const int y0 = blockIdx.y * TH;
    const size_t base = (size_t)blockIdx.z * (size_t)(HH * WW);
    const float* imb = im_in + base;
    const float* peb = pe_in + base;

    const float w28 = 1.0f / 28.0f;   // fp32-rounded, as in the ref kernels
    const float w16 = 0.0625f;        // exact

    // ---- stage raw tile + 6-halo, zero-padded ----
    for (int i = tid; i < SIH * SIW; i += 256) {
        int r = i / SIW;
        int c = i - r * SIW;
        int gy = y0 - 2 * RAD + r;
        int gx = x0 - 2 * RAD + c;
        bool ok = ((unsigned)gy < (unsigned)HH) && ((unsigned)gx < (unsigned)WW);
        int gi = gy * WW + gx;
        sI0[r][c] = ok ? imb[gi] : 0.0f;
        sP0[r][c] = ok ? peb[gi] : 0.0f;
    }
    __syncthreads();

    // ---- iter-a: intermediate on SMH x SMW, flat over threads, fully
    //      inline (R4 load shape: scalar stride-1 reads, 0 conflicts).
    //      Out-of-image px are ZERO (ref's padding for iter-b). ----
    for (int i = tid; i < SMH * SMW; i += 256) {
        int r = i / SMW;             // mid row; image row y0-3+r
        int c = i - r * SMW;         // mid col; image col x0-3+c
        int iy = y0 - RAD + r;
        int ix = x0 - RAD + c;
        bool inside = ((unsigned)iy < (unsigned)HH) && ((unsigned)ix < (unsigned)WW);
        float oI = 0.0f, oP = 0.0f;
        if (inside) {
            // im: 8 exact sequential fma chains, row-major taps
            float sL = 0.f, sR = 0.f, sU = 0.f, sD = 0.f;
            float sNW = 0.f, sNE = 0.f, sSW = 0.f, sSE = 0.f;
            float hl[7], hr[7], cb[7];
            #pragma unroll
            for (int dy = 0; dy < 7; ++dy) {
                float a0 = sI0[r + dy][c],     a1 = sI0[r + dy][c + 1],
                      a2 = sI0[r + dy][c + 2], a3 = sI0[r + dy][c + 3],
                      a4 = sI0[r + dy][c + 4], a5 = sI0[r + dy][c + 5],
                      a6 = sI0[r + dy][c + 6];
                // L: cols 0..3 ; R: cols 3..6 (sequential row-major order)
                sL = fmaf(a0, w28, sL); sL = fmaf(a1, w28, sL);
                sL = fmaf(a2, w28, sL); sL = fmaf(a3, w28, sL);
                sR = fmaf(a3, w28, sR); sR = fmaf(a4, w28, sR);
                sR = fmaf(a5, w28, sR); sR = fmaf(a6, w28, sR);
                if (dy < 4) {
                    sU = fmaf(a0, w28, sU); sU = fmaf(a1, w28, sU);
                    sU = fmaf(a2, w28, sU); sU = fmaf(a3, w28, sU);
                    sU = fmaf(a4, w28, sU); sU = fmaf(a5, w28, sU);
                    sU = fmaf(a6, w28, sU);
                    sNW = fmaf(a0, w16, sNW); sNW = fmaf(a1, w16, sNW);
                    sNW = fmaf(a2, w16, sNW); sNW = fmaf(a3, w16, sNW);
                    sNE = fmaf(a3, w16, sNE); sNE = fmaf(a4, w16, sNE);
                    sNE = fmaf(a5, w16, sNE); sNE = fmaf(a6, w16, sNE);
                }
                if (dy >= 3) {
                    sD = fmaf(a0, w28, sD); sD = fmaf(a1, w28, sD);
                    sD = fmaf(a2, w28, sD); sD = fmaf(a3, w28, sD);
                    sD = fmaf(a4, w28, sD); sD = fmaf(a5, w28, sD);
                    sD = fmaf(a6, w28, sD);
                    sSW = fmaf(a0, w16, sSW); sSW = fmaf(a1, w16, sSW);
                    sSW = fmaf(a2, w16, sSW); sSW = fmaf(a3, w16, sSW);
                    sSE = fmaf(a3, w16, sSE); sSE = fmaf(a4, w16, sSE);
                    sSE = fmaf(a5, w16, sSE); sSE = fmaf(a6, w16, sSE);
                }
                float b0 = sP0[r + dy][c],     b1 = sP0[r + dy][c + 1],
                      b2 = sP0[r + dy][c + 2], b3 = sP0[r + dy][c + 3],
                      b4 = sP0[r + dy][c + 4], b5 = sP0[r + dy][c + 5],
                      b6 = sP0[r + dy][c + 6];
                hl[dy] = (b0 + b1) + (b2 + b3);
                hr[dy] = (b3 + b4) + (b5 + b6);
                cb[dy] = b3;
            }
            const float cI = sI0[r + 3][c + 3];
            float d[8];
            d[0] = sL - cI;  d[1] = sR - cI;  d[2] = sU - cI;  d[3] = sD - cI;
            d[4] = sNW - cI; d[5] = sNE - cI; d[6] = sSW - cI; d[7] = sSE - cI;

            float e[8];
            {
                float qnw = ((hl[0] + hl[1]) + (hl[2] + hl[3]));
                float qsw = ((hl[3] + hl[4]) + (hl[5] + hl[6]));
                float qne = ((hr[0] + hr[1]) + (hr[2] + hr[3]));
                float qse = ((hr[3] + hr[4]) + (hr[5] + hr[6]));
                float cu  = ((cb[0] + cb[1]) + (cb[2] + cb[3]));
                float cd  = ((cb[3] + cb[4]) + (cb[5] + cb[6]));
                float cP  = cb[3];
                e[0] = (qnw + qsw - hl[3]) * w28 - cP;
                e[1] = (qne + qse - hr[3]) * w28 - cP;
                e[2] = (qnw + qne - cu)    * w28 - cP;
                e[3] = (qsw + qse - cd)    * w28 - cP;
                e[4] = qnw * w16 - cP;
                e[5] = qne * w16 - cP;
                e[6] = qsw * w16 - cP;
                e[7] = qse * w16 - cP;
                oP = cP;
            }
            float bestAbs = fabsf(d[0]);
            float bd = d[0];
            float be = e[0];
            #pragma unroll
            for (int j = 1; j < 8; ++j) {
                float a = fabsf(d[j]);
                bool take = a < bestAbs;
                bestAbs = take ? a : bestAbs;
                bd = take ? d[j] : bd;
                be = take ? e[j] : be;
            }
            oI = cI + bd;
            oP += be;
        }
        sIm[r][c] = oI;
        sPm[r][c] = oP;
    }
    __syncthreads();

    // ---- iter-b: core TH x TW, R8's register ring verbatim over sIm/sPm ----
    const int tx = tid & 63;
    const int wv = tid >> 6;
    const int r0 = wv * RPW;

    float wi[7][7];
    float hl[7], hr[7], cc[7];
    #pragma unroll
    for (int m = 0; m < 7; ++m) {
        #pragma unroll
        for (int dx = 0; dx < 7; ++dx)
            wi[m][dx] = sIm[r0 + m][tx + dx];
        float b0 = sPm[r0 + m][tx],     b1 = sPm[r0 + m][tx + 1],
              b2 = sPm[r0 + m][tx + 2], b3 = sPm[r0 + m][tx + 3],
              b4 = sPm[r0 + m][tx + 4], b5 = sPm[r0 + m][tx + 5],
              b6 = sPm[r0 + m][tx + 6];
        hl[m] = (b0 + b1) + (b2 + b3);
        hr[m] = (b3 + b4) + (b5 + b6);
        cc[m] = b3;
    }

    #pragma unroll
    for (int jj = 0; jj < RPW; ++jj) {
        float d[8];
        {
            float sL = 0.f, sR = 0.f, sU = 0.f, sD = 0.f;
            float sNW = 0.f, sNE = 0.f, sSW = 0.f, sSE = 0.f;
            #pragma unroll
            for (int dy = 0; dy < 7; ++dy) {
                const int s = (jj + dy) % 7;
                #pragma unroll
                for (int dx = 0; dx < 4; ++dx)
                    sL = fmaf(wi[s][dx], w28, sL);
                #pragma unroll
                for (int dx = 3; dx < 7; ++dx)
                    sR = fmaf(wi[s][dx], w28, sR);
            }
            #pragma unroll
            for (int dy = 0; dy < 4; ++dy) {
                const int s = (jj + dy) % 7;
                #pragma unroll
                for (int dx = 0; dx < 7; ++dx)
                    sU = fmaf(wi[s][dx], w28, sU);
                #pragma unroll
                for (int dx = 0; dx < 4; ++dx)
                    sNW = fmaf(wi[s][dx], w16, sNW);
                #pragma unroll
                for (int dx = 3; dx < 7; ++dx)
                    sNE = fmaf(wi[s][dx], w16, sNE);
            }
            #pragma unroll
            for (int dy = 3; dy < 7; ++dy) {
                const int s = (jj + dy) % 7;
                #pragma unroll
                for (int dx = 0; dx < 7; ++dx)
                    sD = fmaf(wi[s][dx], w28, sD);
                #pragma unroll
                for (int dx = 0; dx < 4; ++dx)
                    sSW = fmaf(wi[s][dx], w16, sSW);
                #pragma unroll
                for (int dx = 3; dx < 7; ++dx)
                    sSE = fmaf(wi[s][dx], w16, sSE);
            }
            const float cI = wi[(jj + 3) % 7][3];
            d[0] = sL - cI;  d[1] = sR - cI;  d[2] = sU - cI;  d[3] = sD - cI;
            d[4] = sNW - cI; d[5] = sNE - cI; d[6] = sSW - cI; d[7] = sSE - cI;
        }

        float e[8];
        const int p0 = (jj + 0) % 7, p1 = (jj + 1) % 7, p2 = (jj + 2) % 7,
                  p3 = (jj + 3) % 7, p4 = (jj + 4) % 7, p5 = (jj + 5) % 7,
                  p6 = (jj + 6) % 7;
        {
            float qnw = ((hl[p0] + hl[p1]) + (hl[p2] + hl[p3]));
            float qsw = ((hl[p3] + hl[p4]) + (hl[p5] + hl[p6]));
            float qne = ((hr[p0] + hr[p1]) + (hr[p2] + hr[p3]));
            float qse = ((hr[p3] + hr[p4]) + (hr[p5] + hr[p6]));
            float cu  = ((cc[p0] + cc[p1]) + (cc[p2] + cc[p3]));
            float cd  = ((cc[p3] + cc[p4]) + (cc[p5] + cc[p6]));
            float cP  = cc[p3];
            e[0] = (qnw + qsw - hl[p3]) * w28 - cP;
            e[1] = (qne + qse - hr[p3]) * w28 - cP;
            e[2] = (qnw + qne - cu)     * w28 - cP;
            e[3] = (qsw + qse - cd)     * w28 - cP;
            e[4] = qnw * w16 - cP;
            e[5] = qne * w16 - cP;
            e[6] = qsw * w16 - cP;
            e[7] = qse * w16 - cP;
        }

        float bestAbs = fabsf(d[0]);
        float bd = d[0];
        float be = e[0];
        #pragma unroll
        for (int j = 1; j < 8; ++j) {
            float a = fabsf(d[j]);
            bool take = a < bestAbs;
            bestAbs = take ? a : bestAbs;
            bd = take ? d[j] : bd;
            be = take ? e[j] : be;
        }

        const int gy = y0 + r0 + jj;
        const int gx = x0 + tx;
        const size_t gi = base + (size_t)gy * WW + gx;
        if (STORE_IM) im_out[gi] = wi[(jj + 3) % 7][3] + bd;
        pe_out[gi] = cc[p3] + be;

        if (jj < RPW - 1) {
            const int m = r0 + jj + 7;      // <= 21 < SMH
            const int slot = jj % 7;
            #pragma unroll
            for (int dx = 0; dx < 7; ++dx)
                wi[slot][dx] = sIm[m][tx + dx];
            float b0 = sPm[m][tx],     b1 = sPm[m][tx + 1], b2 = sPm[m][tx + 2],
                  b3 = sPm[m][tx + 3], b4 = sPm[m][tx + 4], b5 = sPm[m][tx + 5],
                  b6 = sPm[m][tx + 6];
            hl[slot] = (b0 + b1) + (b2 + b3);
            hr[slot] = (b3 + b4) + (b5 + b6);
            cc[slot] = b3;
        }
    }
}

extern "C" void kernel_launch(void* const* d_in, const int* in_sizes, int n_in,
                              void* d_out, int out_size, void* d_ws, size_t ws_size,
                              hipStream_t stream) {
    const float* im0 = (const float*)d_in[0];
    const float* pe0 = (const float*)d_in[1];
    float* out = (float*)d_out;

    const size_t npix = (size_t)NIMG * HH * WW;   // 3,145,728
    float* imA = (float*)d_ws;                    // 12.6 MB
    float* imB = imA + npix;                      // 12.6 MB
    float* peA = imB + npix;                      // 12.6 MB
    float* peB = peA + npix;                      // 12.6 MB (ws total 50.3 MB)

    dim3 grid(WW / TW, HH / TH, NIMG);            // 8 x 32 x 12 = 3072 blocks
    dim3 block(256);

    // 3 dispatches x 2 fused iterations; final pert lands in d_out, final
    // im store elided (result is pert only).
    swf_fused<true ><<<grid, block, 0, stream>>>(im0, pe0, imA, peA); // it0+1
    swf_fused<true ><<<grid, block, 0, stream>>>(imA, peA, imB, peB); // it2+3
    swf_fused<false><<<grid, block, 0, stream>>>(imB, peB, imA, out); // it4+5
}